// Round 4
// baseline (125.919 us; speedup 1.0000x reference)
//
#include <hip/hip_runtime.h>
#include <math.h>

#define BB 8
#define SS 4096
#define EE 128
#define HH 64
#define LOG2E 1.44269504088896f

typedef _Float16 f16;
typedef __attribute__((ext_vector_type(8))) _Float16 f16x8;
typedef __attribute__((ext_vector_type(2))) _Float16 f16x2;
typedef __attribute__((ext_vector_type(4))) float f32x4;

__device__ __forceinline__ unsigned short f2h(float v) {
    f16 h = (f16)v;
    return __builtin_bit_cast(unsigned short, h);
}
__device__ __forceinline__ unsigned int pk2h(float a, float b) {
    return __builtin_bit_cast(unsigned int, __builtin_amdgcn_cvt_pkrtz(a, b));
}

// ---------------- W transpose+convert setup ----------------
// Wt f16 [192 cols][128 e]: cols 0-63 = Wq*log2e, 64-127 = Wk, 128-191 = Wv.
__global__ __launch_bounds__(256) void wtrans_kernel(
    const float* __restrict__ Wq, const float* __restrict__ Wk,
    const float* __restrict__ Wv, f16* __restrict__ Wt)
{
    const int idx = blockIdx.x * 256 + threadIdx.x;
    if (idx >= 192 * 128) return;
    const int col = idx >> 7, e = idx & 127;
    const float v = (col < 64)  ? Wq[e * 64 + col] * LOG2E
                  : (col < 128) ? Wk[e * 64 + (col - 64)]
                                : Wv[e * 64 + (col - 128)];
    Wt[col * 128 + e] = (f16)v;
}

// ---------------- QKV projection: fp16 MFMA GEMM ----------------
// Q is pre-scaled by log2e (folded into Wq/bq) so flash softmax is exp2-native.
__global__ __launch_bounds__(256) void qkv_kernel(
    const float* __restrict__ x, const f16* __restrict__ Wt,
    const float* __restrict__ bq, const float* __restrict__ bk,
    const float* __restrict__ bv,
    f16* __restrict__ Q, f16* __restrict__ K, f16* __restrict__ Vt)
{
    __shared__ __align__(16) short xs[64 * EE];   // fp16 tile, 256 B rows
    const int tid = threadIdx.x;
    const long rowbase = (long)blockIdx.x * 64;

    {
        const float4* xg = (const float4*)(x + rowbase * EE);
#pragma unroll
        for (int j = 0; j < 8; ++j) {
            const int eidx = tid * 32 + j * 4;
            const float4 v = xg[eidx >> 2];
            unsigned long long pk =
                (unsigned long long)pk2h(v.x, v.y) |
                ((unsigned long long)pk2h(v.z, v.w) << 32);
            const int row = eidx >> 7;
            const int off = (row * 256 + (eidx & 127) * 2) ^ ((row & 7) << 4);
            *(unsigned long long*)((char*)xs + off) = pk;
        }
    }
    __syncthreads();

    const int lane = tid & 63;
    const int wid  = tid >> 6;
    const int ln15 = lane & 15;
    const int lg   = lane >> 4;

    f16x8 xa[4];
    {
        const int row = wid * 16 + ln15;
        const int swz = (row & 7) << 4;
#pragma unroll
        for (int s = 0; s < 4; ++s)
            xa[s] = *(const f16x8*)((const char*)xs + ((row * 256 + lg * 16 + s * 64) ^ swz));
    }

    f32x4 acc[12];
#pragma unroll
    for (int ct = 0; ct < 12; ++ct) acc[ct] = (f32x4){0.f, 0.f, 0.f, 0.f};

#pragma unroll
    for (int ct = 0; ct < 12; ++ct) {
        const f16* wtp = Wt + (ct * 16 + ln15) * 128 + lg * 8;
#pragma unroll
        for (int s = 0; s < 4; ++s) {
            const f16x8 wb = *(const f16x8*)(wtp + s * 32);
            acc[ct] = __builtin_amdgcn_mfma_f32_16x16x32_f16(xa[s], wb, acc[ct], 0, 0, 0);
        }
    }

    const long grow0 = rowbase + wid * 16 + 4 * lg;
#pragma unroll
    for (int ct = 0; ct < 4; ++ct) {
        const int col = ct * 16 + ln15;
        const float b = bq[col] * LOG2E;
#pragma unroll
        for (int r = 0; r < 4; ++r)
            Q[(grow0 + r) * HH + col] = (f16)(acc[ct][r] + b);
    }
#pragma unroll
    for (int ct = 4; ct < 8; ++ct) {
        const int col = (ct - 4) * 16 + ln15;
        const float b = bk[col];
#pragma unroll
        for (int r = 0; r < 4; ++r)
            K[(grow0 + r) * HH + col] = (f16)(acc[ct][r] + b);
    }
    {
        const long batch = rowbase >> 12;
        const long inrow = (rowbase & 4095) + wid * 16 + 4 * lg;
#pragma unroll
        for (int ct = 8; ct < 12; ++ct) {
            const int o = (ct - 8) * 16 + ln15;
            const float b = bv[o];
            unsigned long long pk =
                (unsigned long long)pk2h(acc[ct][0] + b, acc[ct][1] + b) |
                ((unsigned long long)pk2h(acc[ct][2] + b, acc[ct][3] + b) << 32);
            *(unsigned long long*)(Vt + ((long)batch * HH + o) * SS + inrow) = pk;
        }
    }
}

// ---------------- MFMA flash attention, fp16, exp2-domain, split-K4 ----------------
// grid 1024 = 8 batch (XCD-affine) x 4 split x 32 qblk; 512 thr = 8 waves.
// Wave = 16 q rows, block = 128 q rows. KV tile = 64 keys, 16 tiles/block.
// 32 KB LDS -> 4 blocks/CU -> 32 waves/CU. T14 async stage, T13 defer-max,
// T5 setprio. Partials: normalized f16 O + log2-LSE.
__global__ __launch_bounds__(512, 8) void flash_kernel(
    const f16* __restrict__ Q, const f16* __restrict__ K,
    const f16* __restrict__ Vt, f16* __restrict__ Onorm,
    float* __restrict__ lse)
{
    __shared__ __align__(16) short k_s[64 * HH];      // 8 KB
    __shared__ __align__(16) short v_s[64 * HH];      // 8 KB  [o][key]
    __shared__ __align__(16) short p_s[8 * 16 * HH];  // 16 KB per-wave P

    const int tid  = threadIdx.x;
    const int lane = tid & 63;
    const int wid  = tid >> 6;
    const int ln15 = lane & 15;
    const int lg   = lane >> 4;
    const int batch = blockIdx.x & 7;
    const int rest  = blockIdx.x >> 3;
    const int split = rest & 3;
    const int qblk  = rest >> 2;
    const int k0base = split * (SS / 4);

    f16x8 qf[2];
    {
        const long qrow = (long)batch * SS + qblk * 128 + wid * 16 + ln15;
        const f16* qp = Q + qrow * HH + lg * 8;
        qf[0] = *(const f16x8*)(qp);
        qf[1] = *(const f16x8*)(qp + 32);
    }

    f32x4 oacc[4];
#pragma unroll
    for (int ot = 0; ot < 4; ++ot) oacc[ot] = (f32x4){0.f, 0.f, 0.f, 0.f};
    float m = -1e30f, l = 0.f;

    short* pw = p_s + wid * (16 * HH);
    const int swq = (ln15 & 7) << 4;

    // staging: 512 16B chunks per 8KB tile, exactly 1 per thread per array
    const int srow = tid >> 3;
    const int scc  = tid & 7;
    const int d0 = (srow * 128 + scc * 16) ^ ((srow & 7) << 4);

    const uint4* kb = (const uint4*)(K + ((long)batch * SS + k0base) * HH);
    const f16* vbase = Vt + (long)batch * HH * SS + k0base;

    uint4 kr, vr;
    kr = kb[tid];
    vr = *(const uint4*)(vbase + (long)srow * SS + scc * 8);
    *(uint4*)((char*)k_s + d0) = kr;
    *(uint4*)((char*)v_s + d0) = vr;
    __syncthreads();

    for (int t = 0; t < 16; ++t) {
        // T14: issue next tile's global loads now, ds_write after the barrier
        if (t + 1 < 16) {
            kr = kb[tid + (t + 1) * 512];
            vr = *(const uint4*)(vbase + (t + 1) * 64 + (long)srow * SS + scc * 8);
        }

        // ---- QK^T (swapped: A = K rows, B = Q), scores in log2 domain ----
        f32x4 sacc[4];
        __builtin_amdgcn_s_setprio(1);
#pragma unroll
        for (int kt = 0; kt < 4; ++kt) {
            f32x4 a = (f32x4){0.f, 0.f, 0.f, 0.f};
            const int key = kt * 16 + ln15;
            const int rb = key * 128, swz = (key & 7) << 4;
#pragma unroll
            for (int s = 0; s < 2; ++s) {
                const f16x8 ka = *(const f16x8*)((const char*)k_s + ((rb + lg * 16 + s * 64) ^ swz));
                a = __builtin_amdgcn_mfma_f32_16x16x32_f16(ka, qf[s], a, 0, 0, 0);
            }
            sacc[kt] = a;
        }
        __builtin_amdgcn_s_setprio(0);

        // ---- online softmax (exp2 domain), defer-max thr = 8*log2e ----
        float t0 = fmaxf(fmaxf(sacc[0][0], sacc[0][1]), sacc[0][2]);
        float t1 = fmaxf(fmaxf(sacc[0][3], sacc[1][0]), sacc[1][1]);
        float t2 = fmaxf(fmaxf(sacc[1][2], sacc[1][3]), sacc[2][0]);
        float t3 = fmaxf(fmaxf(sacc[2][1], sacc[2][2]), sacc[2][3]);
        float t4 = fmaxf(fmaxf(sacc[3][0], sacc[3][1]), sacc[3][2]);
        float tm = fmaxf(fmaxf(fmaxf(t0, t1), t2), fmaxf(fmaxf(t3, t4), sacc[3][3]));
        tm = fmaxf(tm, __shfl_xor(tm, 16));
        tm = fmaxf(tm, __shfl_xor(tm, 32));
        if (!__all(tm <= m + 11.5f)) {
            const float mn = fmaxf(m, tm);
            const float alpha = __builtin_amdgcn_exp2f(m - mn);
            l *= alpha;
#pragma unroll
            for (int r = 0; r < 4; ++r) {
                const float ar = __shfl(alpha, lg * 4 + r);
                oacc[0][r] *= ar; oacc[1][r] *= ar;
                oacc[2][r] *= ar; oacc[3][r] *= ar;
            }
            m = mn;
        }

        float ps = 0.f;
#pragma unroll
        for (int kt = 0; kt < 4; ++kt)
#pragma unroll
            for (int r = 0; r < 4; ++r) {
                const float pv = __builtin_amdgcn_exp2f(sacc[kt][r] - m);
                sacc[kt][r] = pv;
                ps += pv;
            }
        ps += __shfl_xor(ps, 16);
        ps += __shfl_xor(ps, 32);
        l += ps;

        // P -> wave-private LDS: row q = ln15, key = 16kt + 4lg + r, b64 writes
#pragma unroll
        for (int kt = 0; kt < 4; ++kt) {
            uint2 pk;
            pk.x = pk2h(sacc[kt][0], sacc[kt][1]);
            pk.y = pk2h(sacc[kt][2], sacc[kt][3]);
            const int key = kt * 16 + lg * 4;
            *(uint2*)((char*)pw + ((ln15 * 128 + key * 2) ^ swq)) = pk;
        }

        // ---- O += P.V ----
        __builtin_amdgcn_s_setprio(1);
#pragma unroll
        for (int s = 0; s < 2; ++s) {
            const f16x8 pa = *(const f16x8*)((const char*)pw + ((ln15 * 128 + lg * 16 + s * 64) ^ swq));
#pragma unroll
            for (int ot = 0; ot < 4; ++ot) {
                const int o = ot * 16 + ln15;
                const f16x8 vb = *(const f16x8*)((const char*)v_s + ((o * 128 + lg * 16 + s * 64) ^ ((o & 7) << 4)));
                oacc[ot] = __builtin_amdgcn_mfma_f32_16x16x32_f16(pa, vb, oacc[ot], 0, 0, 0);
            }
        }
        __builtin_amdgcn_s_setprio(0);

        __syncthreads();
        if (t + 1 < 16) {
            *(uint4*)((char*)k_s + d0) = kr;
            *(uint4*)((char*)v_s + d0) = vr;
        }
        __syncthreads();
    }

    // epilogue: normalized f16 partials + log2-LSE
    const float linv = 1.0f / l;
    const long ridx = (long)split * (BB * SS) + (long)batch * SS + qblk * 128 + wid * 16;
#pragma unroll
    for (int r = 0; r < 4; ++r) {
        const float ir = __shfl(linv, lg * 4 + r);
        f16* op = Onorm + (ridx + lg * 4 + r) * HH + ln15;
        op[0]  = (f16)(oacc[0][r] * ir);
        op[16] = (f16)(oacc[1][r] * ir);
        op[32] = (f16)(oacc[2][r] * ir);
        op[48] = (f16)(oacc[3][r] * ir);
    }
    if (lg == 0)
        lse[ridx + ln15] = m + __builtin_amdgcn_logf(l);
}

// ---------------- split-K merge (log2-LSE weighted) ----------------
__global__ __launch_bounds__(256) void merge_kernel(
    const f16* __restrict__ Onorm, const float* __restrict__ lse,
    float* __restrict__ Out)
{
    const int gid = blockIdx.x * 256 + threadIdx.x;   // 32768 rows x 8 col-groups
    const long row = gid >> 3;
    const int c0 = (gid & 7) * 8;
    const long NR = (long)BB * SS;

    float ls[4];
#pragma unroll
    for (int i = 0; i < 4; ++i) ls[i] = lse[i * NR + row];
    const float M = fmaxf(fmaxf(ls[0], ls[1]), fmaxf(ls[2], ls[3]));
    float g[4], denom = 0.f;
#pragma unroll
    for (int i = 0; i < 4; ++i) { g[i] = __builtin_amdgcn_exp2f(ls[i] - M); denom += g[i]; }
    const float inv = 1.0f / denom;

    float acc[8];
#pragma unroll
    for (int j = 0; j < 8; ++j) acc[j] = 0.f;
#pragma unroll
    for (int i = 0; i < 4; ++i) {
        const f16x8 o = *(const f16x8*)(Onorm + (i * NR + row) * HH + c0);
#pragma unroll
        for (int j = 0; j < 8; ++j) acc[j] = fmaf(g[i], (float)o[j], acc[j]);
    }
    float4 r0, r1;
    r0.x = acc[0] * inv; r0.y = acc[1] * inv; r0.z = acc[2] * inv; r0.w = acc[3] * inv;
    r1.x = acc[4] * inv; r1.y = acc[5] * inv; r1.z = acc[6] * inv; r1.w = acc[7] * inv;
    float4* dst = (float4*)(Out + row * HH + c0);
    dst[0] = r0;
    dst[1] = r1;
}

extern "C" void kernel_launch(void* const* d_in, const int* in_sizes, int n_in,
                              void* d_out, int out_size, void* d_ws, size_t ws_size,
                              hipStream_t stream) {
    const float* x  = (const float*)d_in[0];
    const float* Wq = (const float*)d_in[1];
    const float* bq = (const float*)d_in[2];
    const float* Wk = (const float*)d_in[3];
    const float* bk = (const float*)d_in[4];
    const float* Wv = (const float*)d_in[5];
    const float* bv = (const float*)d_in[6];
    float* out = (float*)d_out;

    // ws: Q f16 4MB | K f16 4MB | Vt f16 4MB | Wt 48KB | Onorm f16 16MB | lse f32 512KB
    const size_t NTOK = (size_t)BB * SS;
    f16* Q  = (f16*)d_ws;
    f16* K  = Q + NTOK * HH;
    f16* Vt = K + NTOK * HH;
    f16* Wt = Vt + NTOK * HH;
    f16* Onorm = Wt + 192 * 128;
    float* lse = (float*)(Onorm + 4 * NTOK * HH);

    wtrans_kernel<<<96, 256, 0, stream>>>(Wq, Wk, Wv, Wt);
    qkv_kernel<<<BB * SS / 64, 256, 0, stream>>>(x, Wt, bq, bk, bv, Q, K, Vt);
    flash_kernel<<<BB * 4 * (SS / 128), 512, 0, stream>>>(Q, K, Vt, Onorm, lse);
    merge_kernel<<<BB * SS * 8 / 256, 256, 0, stream>>>(Onorm, lse, out);
}

// Round 5
// 89.111 us; speedup vs baseline: 1.4131x; 1.4131x over previous
//
#include <hip/hip_runtime.h>
#include <math.h>

#define BB 8
#define SS 4096
#define EE 128
#define HH 64
#define NT 16   // KV tiles per flash block (split-K4: 1024 keys / 64)
#define LOG2E 1.44269504088896f

typedef _Float16 f16;
typedef __attribute__((ext_vector_type(8))) _Float16 f16x8;
typedef __attribute__((ext_vector_type(4))) float f32x4;

__device__ __forceinline__ unsigned int pk2h(float a, float b) {
    return __builtin_bit_cast(unsigned int, __builtin_amdgcn_cvt_pkrtz(a, b));
}

// one barrier per tile WITHOUT draining vmcnt (prefetch loads stay in flight)
__device__ __forceinline__ void tile_barrier() {
    asm volatile("s_waitcnt lgkmcnt(0)" ::: "memory");
    __builtin_amdgcn_s_barrier();
    __builtin_amdgcn_sched_barrier(0);
}

// ---------------- W transpose+convert setup ----------------
// Wt f16 [192 cols][128 e]: cols 0-63 = Wq*log2e, 64-127 = Wk, 128-191 = Wv.
__global__ __launch_bounds__(256) void wtrans_kernel(
    const float* __restrict__ Wq, const float* __restrict__ Wk,
    const float* __restrict__ Wv, f16* __restrict__ Wt)
{
    const int idx = blockIdx.x * 256 + threadIdx.x;
    if (idx >= 192 * 128) return;
    const int col = idx >> 7, e = idx & 127;
    const float v = (col < 64)  ? Wq[e * 64 + col] * LOG2E
                  : (col < 128) ? Wk[e * 64 + (col - 64)]
                                : Wv[e * 64 + (col - 128)];
    Wt[col * 128 + e] = (f16)v;
}

// ---------------- QKV projection: fp16 MFMA GEMM ----------------
// Q pre-scaled by log2e (folded into Wq/bq) -> flash softmax is exp2-native.
__global__ __launch_bounds__(256) void qkv_kernel(
    const float* __restrict__ x, const f16* __restrict__ Wt,
    const float* __restrict__ bq, const float* __restrict__ bk,
    const float* __restrict__ bv,
    f16* __restrict__ Q, f16* __restrict__ K, f16* __restrict__ Vt)
{
    __shared__ __align__(16) short xs[64 * EE];   // fp16 tile, 256 B rows
    const int tid = threadIdx.x;
    const long rowbase = (long)blockIdx.x * 64;

    {
        const float4* xg = (const float4*)(x + rowbase * EE);
#pragma unroll
        for (int j = 0; j < 8; ++j) {
            const int eidx = tid * 32 + j * 4;
            const float4 v = xg[eidx >> 2];
            unsigned long long pk =
                (unsigned long long)pk2h(v.x, v.y) |
                ((unsigned long long)pk2h(v.z, v.w) << 32);
            const int row = eidx >> 7;
            const int off = (row * 256 + (eidx & 127) * 2) ^ ((row & 7) << 4);
            *(unsigned long long*)((char*)xs + off) = pk;
        }
    }
    __syncthreads();

    const int lane = tid & 63;
    const int wid  = tid >> 6;
    const int ln15 = lane & 15;
    const int lg   = lane >> 4;

    f16x8 xa[4];
    {
        const int row = wid * 16 + ln15;
        const int swz = (row & 7) << 4;
#pragma unroll
        for (int s = 0; s < 4; ++s)
            xa[s] = *(const f16x8*)((const char*)xs + ((row * 256 + lg * 16 + s * 64) ^ swz));
    }

    f32x4 acc[12];
#pragma unroll
    for (int ct = 0; ct < 12; ++ct) acc[ct] = (f32x4){0.f, 0.f, 0.f, 0.f};

#pragma unroll
    for (int ct = 0; ct < 12; ++ct) {
        const f16* wtp = Wt + (ct * 16 + ln15) * 128 + lg * 8;
#pragma unroll
        for (int s = 0; s < 4; ++s) {
            const f16x8 wb = *(const f16x8*)(wtp + s * 32);
            acc[ct] = __builtin_amdgcn_mfma_f32_16x16x32_f16(xa[s], wb, acc[ct], 0, 0, 0);
        }
    }

    const long grow0 = rowbase + wid * 16 + 4 * lg;
#pragma unroll
    for (int ct = 0; ct < 4; ++ct) {
        const int col = ct * 16 + ln15;
        const float b = bq[col] * LOG2E;
#pragma unroll
        for (int r = 0; r < 4; ++r)
            Q[(grow0 + r) * HH + col] = (f16)(acc[ct][r] + b);
    }
#pragma unroll
    for (int ct = 4; ct < 8; ++ct) {
        const int col = (ct - 4) * 16 + ln15;
        const float b = bk[col];
#pragma unroll
        for (int r = 0; r < 4; ++r)
            K[(grow0 + r) * HH + col] = (f16)(acc[ct][r] + b);
    }
    {
        const long batch = rowbase >> 12;
        const long inrow = (rowbase & 4095) + wid * 16 + 4 * lg;
#pragma unroll
        for (int ct = 8; ct < 12; ++ct) {
            const int o = (ct - 8) * 16 + ln15;
            const float b = bv[o];
            unsigned long long pk =
                (unsigned long long)pk2h(acc[ct][0] + b, acc[ct][1] + b) |
                ((unsigned long long)pk2h(acc[ct][2] + b, acc[ct][3] + b) << 32);
            *(unsigned long long*)(Vt + ((long)batch * HH + o) * SS + inrow) = pk;
        }
    }
}

// ---------------- MFMA flash attention, fp16, exp2-domain, split-K4 ----------------
// grid 2048 = 8 batch (XCD-affine) x 4 split x 64 qtile; 256 thr = 4 waves.
// Wave = 16 q rows. KV tile = 64 keys, double-buffered LDS, ONE raw barrier
// per tile (vmcnt never drained -> 2-deep load pipeline, T4). T14 reg-stage,
// T13 defer-max, T5 setprio. Partials: normalized f16 O + log2-LSE.
__global__ __launch_bounds__(256, 4) void flash_kernel(
    const f16* __restrict__ Q, const f16* __restrict__ K,
    const f16* __restrict__ Vt, f16* __restrict__ Onorm,
    float* __restrict__ lse)
{
    __shared__ __align__(16) short k_s[2][64 * HH];   // 2 x 8 KB
    __shared__ __align__(16) short v_s[2][64 * HH];   // 2 x 8 KB  [o][key]
    __shared__ __align__(16) short p_s[4 * 16 * HH];  // 8 KB per-wave P

    const int tid  = threadIdx.x;
    const int lane = tid & 63;
    const int wid  = tid >> 6;
    const int ln15 = lane & 15;
    const int lg   = lane >> 4;
    const int batch = blockIdx.x & 7;
    const int rest  = blockIdx.x >> 3;
    const int split = rest & 3;
    const int qtile = rest >> 2;
    const int k0base = split * (SS / 4);

    // Q fragments (B-operand): col q = ln15, k = s*32 + lg*8 + j
    f16x8 qf[2];
    {
        const long qrow = (long)batch * SS + qtile * 64 + wid * 16 + ln15;
        const f16* qp = Q + qrow * HH + lg * 8;
        qf[0] = *(const f16x8*)(qp);
        qf[1] = *(const f16x8*)(qp + 32);
    }

    f32x4 oacc[4];
#pragma unroll
    for (int ot = 0; ot < 4; ++ot) oacc[ot] = (f32x4){0.f, 0.f, 0.f, 0.f};
    float m = -1e30f, l = 0.f;

    short* pw = p_s + wid * (16 * HH);
    const int swq = (ln15 & 7) << 4;

    // staging geometry: 512 16B chunks per 8 KB tile, 2 per thread
    const int row0 = tid >> 3;            // chunk row (key for K, o for V)
    const int row1 = row0 + 32;
    const int cc0  = (tid & 7) * 16;      // byte offset within 128 B row
    const int dk0 = (row0 * 128 + cc0) ^ ((row0 & 7) << 4);
    const int dk1 = (row1 * 128 + cc0) ^ ((row1 & 7) << 4);

    const uint4* kb  = (const uint4*)(K + ((long)batch * SS + k0base) * HH);
    const f16* vbase = Vt + (long)batch * HH * SS + k0base + (tid & 7) * 8;

    uint4 kA0, kA1, vA0, vA1, kB0, kB1, vB0, vB1;

#define LOADT(t, k0r, k1r, v0r, v1r)                                   \
    do {                                                               \
        const uint4* kp = kb + (t) * 512 + tid;                        \
        k0r = kp[0];                                                   \
        k1r = kp[256];                                                 \
        const f16* vp = vbase + (t) * 64 + (long)row0 * SS;            \
        v0r = *(const uint4*)vp;                                       \
        v1r = *(const uint4*)(vp + 32 * SS);                           \
    } while (0)

#define WRITET(buf, k0r, k1r, v0r, v1r)                                \
    do {                                                               \
        *(uint4*)((char*)k_s[buf] + dk0) = k0r;                        \
        *(uint4*)((char*)k_s[buf] + dk1) = k1r;                        \
        *(uint4*)((char*)v_s[buf] + dk0) = v0r;                        \
        *(uint4*)((char*)v_s[buf] + dk1) = v1r;                        \
    } while (0)

    // compute one 64-key tile from buffer `cur` (literal 0/1 at call sites)
    auto compute = [&](int cur) __attribute__((always_inline)) {
        const short* ks = k_s[cur];
        const short* vs = v_s[cur];

        // ---- QK^T (swapped: A = K rows, B = Q), scores in log2 domain ----
        f32x4 sacc[4];
        __builtin_amdgcn_s_setprio(1);
#pragma unroll
        for (int kt = 0; kt < 4; ++kt) {
            f32x4 a = (f32x4){0.f, 0.f, 0.f, 0.f};
            const int key = kt * 16 + ln15;
            const int rb = key * 128, swz = (key & 7) << 4;
            const f16x8 ka0 = *(const f16x8*)((const char*)ks + ((rb + lg * 16) ^ swz));
            const f16x8 ka1 = *(const f16x8*)((const char*)ks + ((rb + lg * 16 + 64) ^ swz));
            a = __builtin_amdgcn_mfma_f32_16x16x32_f16(ka0, qf[0], a, 0, 0, 0);
            a = __builtin_amdgcn_mfma_f32_16x16x32_f16(ka1, qf[1], a, 0, 0, 0);
            sacc[kt] = a;
        }
        __builtin_amdgcn_s_setprio(0);

        // ---- online softmax (exp2 domain), defer-max thr = 8*log2e ----
        float t0 = fmaxf(fmaxf(sacc[0][0], sacc[0][1]), sacc[0][2]);
        float t1 = fmaxf(fmaxf(sacc[0][3], sacc[1][0]), sacc[1][1]);
        float t2 = fmaxf(fmaxf(sacc[1][2], sacc[1][3]), sacc[2][0]);
        float t3 = fmaxf(fmaxf(sacc[2][1], sacc[2][2]), sacc[2][3]);
        float t4 = fmaxf(fmaxf(sacc[3][0], sacc[3][1]), sacc[3][2]);
        float tm = fmaxf(fmaxf(fmaxf(t0, t1), t2), fmaxf(fmaxf(t3, t4), sacc[3][3]));
        tm = fmaxf(tm, __shfl_xor(tm, 16));
        tm = fmaxf(tm, __shfl_xor(tm, 32));
        if (!__all(tm <= m + 11.5f)) {
            const float mn = fmaxf(m, tm);
            const float alpha = __builtin_amdgcn_exp2f(m - mn);
            l *= alpha;
#pragma unroll
            for (int r = 0; r < 4; ++r) {
                const float ar = __shfl(alpha, lg * 4 + r);
                oacc[0][r] *= ar; oacc[1][r] *= ar;
                oacc[2][r] *= ar; oacc[3][r] *= ar;
            }
            m = mn;
        }

        float ps = 0.f;
#pragma unroll
        for (int kt = 0; kt < 4; ++kt)
#pragma unroll
            for (int r = 0; r < 4; ++r) {
                const float pv = __builtin_amdgcn_exp2f(sacc[kt][r] - m);
                sacc[kt][r] = pv;
                ps += pv;
            }
        ps += __shfl_xor(ps, 16);
        ps += __shfl_xor(ps, 32);
        l += ps;

        // P -> wave-private LDS: row q = ln15, key = 16kt + 4lg + r, b64 writes
#pragma unroll
        for (int kt = 0; kt < 4; ++kt) {
            uint2 pk;
            pk.x = pk2h(sacc[kt][0], sacc[kt][1]);
            pk.y = pk2h(sacc[kt][2], sacc[kt][3]);
            const int key = kt * 16 + lg * 4;
            *(uint2*)((char*)pw + ((ln15 * 128 + key * 2) ^ swq)) = pk;
        }

        // ---- O += P.V ----
        __builtin_amdgcn_s_setprio(1);
#pragma unroll
        for (int s = 0; s < 2; ++s) {
            const f16x8 pa = *(const f16x8*)((const char*)pw + ((ln15 * 128 + lg * 16 + s * 64) ^ swq));
#pragma unroll
            for (int ot = 0; ot < 4; ++ot) {
                const int o = ot * 16 + ln15;
                const f16x8 vb = *(const f16x8*)((const char*)vs + ((o * 128 + lg * 16 + s * 64) ^ ((o & 7) << 4)));
                oacc[ot] = __builtin_amdgcn_mfma_f32_16x16x32_f16(pa, vb, oacc[ot], 0, 0, 0);
            }
        }
        __builtin_amdgcn_s_setprio(0);
    };

    // prologue: tile0 -> buf0, tile1 -> regs A, one full sync
    LOADT(0, kA0, kA1, vA0, vA1);
    WRITET(0, kA0, kA1, vA0, vA1);
    LOADT(1, kA0, kA1, vA0, vA1);
    __syncthreads();

    for (int t = 0; t < NT; t += 2) {
        // even tile t: buf0; regs A hold t+1; prefetch t+2 into B
        compute(0);
        if (t + 2 < NT) LOADT(t + 2, kB0, kB1, vB0, vB1);
        WRITET(1, kA0, kA1, vA0, vA1);        // t+1 <= NT-1 always (NT even)
        tile_barrier();

        // odd tile t+1: buf1; regs B hold t+2; prefetch t+3 into A
        compute(1);
        if (t + 3 < NT) LOADT(t + 3, kA0, kA1, vA0, vA1);
        if (t + 2 < NT) WRITET(0, kB0, kB1, vB0, vB1);
        tile_barrier();
    }
#undef LOADT
#undef WRITET

    // epilogue: normalized f16 partials + log2-LSE
    const float linv = 1.0f / l;
    const long ridx = (long)split * (BB * SS) + (long)batch * SS + qtile * 64 + wid * 16;
#pragma unroll
    for (int r = 0; r < 4; ++r) {
        const float ir = __shfl(linv, lg * 4 + r);
        f16* op = Onorm + (ridx + lg * 4 + r) * HH + ln15;
        op[0]  = (f16)(oacc[0][r] * ir);
        op[16] = (f16)(oacc[1][r] * ir);
        op[32] = (f16)(oacc[2][r] * ir);
        op[48] = (f16)(oacc[3][r] * ir);
    }
    if (lg == 0)
        lse[ridx + ln15] = m + __builtin_amdgcn_logf(l);
}

// ---------------- split-K merge (log2-LSE weighted) ----------------
__global__ __launch_bounds__(256) void merge_kernel(
    const f16* __restrict__ Onorm, const float* __restrict__ lse,
    float* __restrict__ Out)
{
    const int gid = blockIdx.x * 256 + threadIdx.x;   // 32768 rows x 8 col-groups
    const long row = gid >> 3;
    const int c0 = (gid & 7) * 8;
    const long NR = (long)BB * SS;

    float ls[4];
#pragma unroll
    for (int i = 0; i < 4; ++i) ls[i] = lse[i * NR + row];
    const float M = fmaxf(fmaxf(ls[0], ls[1]), fmaxf(ls[2], ls[3]));
    float g[4], denom = 0.f;
#pragma unroll
    for (int i = 0; i < 4; ++i) { g[i] = __builtin_amdgcn_exp2f(ls[i] - M); denom += g[i]; }
    const float inv = 1.0f / denom;

    float acc[8];
#pragma unroll
    for (int j = 0; j < 8; ++j) acc[j] = 0.f;
#pragma unroll
    for (int i = 0; i < 4; ++i) {
        const f16x8 o = *(const f16x8*)(Onorm + (i * NR + row) * HH + c0);
#pragma unroll
        for (int j = 0; j < 8; ++j) acc[j] = fmaf(g[i], (float)o[j], acc[j]);
    }
    float4 r0, r1;
    r0.x = acc[0] * inv; r0.y = acc[1] * inv; r0.z = acc[2] * inv; r0.w = acc[3] * inv;
    r1.x = acc[4] * inv; r1.y = acc[5] * inv; r1.z = acc[6] * inv; r1.w = acc[7] * inv;
    float4* dst = (float4*)(Out + row * HH + c0);
    dst[0] = r0;
    dst[1] = r1;
}

extern "C" void kernel_launch(void* const* d_in, const int* in_sizes, int n_in,
                              void* d_out, int out_size, void* d_ws, size_t ws_size,
                              hipStream_t stream) {
    const float* x  = (const float*)d_in[0];
    const float* Wq = (const float*)d_in[1];
    const float* bq = (const float*)d_in[2];
    const float* Wk = (const float*)d_in[3];
    const float* bk = (const float*)d_in[4];
    const float* Wv = (const float*)d_in[5];
    const float* bv = (const float*)d_in[6];
    float* out = (float*)d_out;

    // ws: Q f16 4MB | K f16 4MB | Vt f16 4MB | Wt 48KB | Onorm f16 16MB | lse f32 512KB
    const size_t NTOK = (size_t)BB * SS;
    f16* Q  = (f16*)d_ws;
    f16* K  = Q + NTOK * HH;
    f16* Vt = K + NTOK * HH;
    f16* Wt = Vt + NTOK * HH;
    f16* Onorm = Wt + 192 * 128;
    float* lse = (float*)(Onorm + 4 * NTOK * HH);

    wtrans_kernel<<<96, 256, 0, stream>>>(Wq, Wk, Wv, Wt);
    qkv_kernel<<<BB * SS / 64, 256, 0, stream>>>(x, Wt, bq, bk, bv, Q, K, Vt);
    flash_kernel<<<BB * 4 * (SS / 64), 256, 0, stream>>>(Q, K, Vt, Onorm, lse);
    merge_kernel<<<BB * SS * 8 / 256, 256, 0, stream>>>(Onorm, lse, out);
}